// Round 1
// baseline (492.047 us; speedup 1.0000x reference)
//
#include <hip/hip_runtime.h>
#include <math.h>

#define THREADS 256
#define NPAIR (8*256*256)

// Packed weights built by prep_kernel (avoids depending on ws_size).
// g_W1T[k][0..8] = W1[:,k], g_W1T[k][9] = b1[k], rest 0.  (64 rows x 16 floats)
__device__ float g_W1T[64 * 16];
// g_Wg1T[u][j] = Wg1[j][u]   (64 rows x 128 floats)
__device__ float g_Wg1T[64 * 128];
// g_gw[k] = ln_gamma[k] * Wo[k]
__device__ float g_gw[64];
// g_cc[0] = sum_k ln_beta[k]*Wo[k], g_cc[1] = sum_k ln_gamma[k]*Wo[k]
__device__ float g_cc[2];

__global__ void prep_kernel(const float* __restrict__ W1, const float* __restrict__ b1,
                            const float* __restrict__ Wg1,
                            const float* __restrict__ ln_g, const float* __restrict__ ln_b,
                            const float* __restrict__ Wo)
{
    int t = threadIdx.x;
    for (int i = t; i < 64 * 16; i += THREADS) {
        int k = i >> 4, j = i & 15;
        float v = 0.f;
        if (j < 9)       v = W1[j * 64 + k];
        else if (j == 9) v = b1[k];
        g_W1T[i] = v;
    }
    for (int i = t; i < 64 * 128; i += THREADS) {
        int u = i >> 7, j = i & 127;
        g_Wg1T[i] = Wg1[j * 64 + u];
    }
    if (t < 64) g_gw[t] = ln_g[t] * Wo[t];
    if (t == 0) {
        float c0 = 0.f, c1 = 0.f;
        for (int k = 0; k < 64; ++k) { c0 += ln_b[k] * Wo[k]; c1 += ln_g[k] * Wo[k]; }
        g_cc[0] = c0; g_cc[1] = c1;
    }
}

__device__ __forceinline__ void build_feat(float x, float s, float xf[9])
{
    xf[0] = x * s;
#pragma unroll
    for (int q = 0; q < 4; ++q) {
        float f = (float)(1 << q);
        xf[1 + 2 * q] = __sinf(x * f) * s;
        xf[2 + 2 * q] = __cosf(x * f) * s;
    }
}

// e[c] = film: silu(x@W1+b1) @ W2 + b2, then *fg + fb.  L1 fused into the k-loop.
__device__ __forceinline__ void encode_channel(const float xf[9],
                                               const float* __restrict__ W2,
                                               const float* __restrict__ b2,
                                               const float* __restrict__ fg,
                                               const float* __restrict__ fb,
                                               float e[64])
{
#pragma unroll
    for (int c = 0; c < 64; ++c) e[c] = b2[c];
    for (int k = 0; k < 64; ++k) {            // dynamic loop: small I-cache footprint
        const float* w1r = &g_W1T[k * 16];    // uniform address -> s_load
        float h = w1r[9];
#pragma unroll
        for (int j = 0; j < 9; ++j) h = fmaf(xf[j], w1r[j], h);
        // silu(h) = h * sigmoid(h)
        h = h * __builtin_amdgcn_rcpf(1.f + __expf(-h));
        const float* w2r = W2 + k * 64;       // uniform address -> s_load
#pragma unroll
        for (int c = 0; c < 64; ++c) e[c] = fmaf(h, w2r[c], e[c]);
    }
#pragma unroll
    for (int c = 0; c < 64; ++c) e[c] = fmaf(e[c], fg[c], fb[c]);
}

__global__ __launch_bounds__(THREADS) void fused_kernel(
    const float* __restrict__ coords, const float* __restrict__ cost,
    const float* __restrict__ lscale,
    const float* __restrict__ W2, const float* __restrict__ b2,
    const float* __restrict__ fgam, const float* __restrict__ fbet,
    const float* __restrict__ bg1, const float* __restrict__ Wg2,
    const float* __restrict__ bg2, const float* __restrict__ gtemp,
    const float* __restrict__ bo,
    float* __restrict__ out)
{
    int p = blockIdx.x * THREADS + threadIdx.x;
    int b = p >> 16;
    int ij = p & 0xFFFF;
    int i = ij >> 8, j = ij & 255;

    float c = cost[p];
    const float* cb = coords + (b << 9);      // 256*2 floats per batch
    float xi = cb[2 * i], yi = cb[2 * i + 1];
    float xj = cb[2 * j], yj = cb[2 * j + 1];
    float ang = atan2f(yi - yj, xi - xj);     // diff[...,1]=dy, diff[...,0]=dx

    float s0 = __expf(lscale[0]);
    float s1 = __expf(lscale[1]);

    float xf[9];
    float e0[64], e1[64];

    build_feat(c, s0, xf);
    encode_channel(xf, W2, b2, fgam, fbet, e0);
    build_feat(ang, s1, xf);
    encode_channel(xf, W2, b2, fgam + 64, fbet + 64, e1);

    // Gate: logits = silu([e0|e1] @ Wg1 + bg1) @ Wg2 + bg2  (g_u streamed, never stored)
    float l0 = bg2[0], l1 = bg2[1];
    for (int u = 0; u < 64; ++u) {
        const float* wr = &g_Wg1T[u * 128];   // uniform -> s_load
        float g = bg1[u];
#pragma unroll
        for (int k = 0; k < 64; ++k) g = fmaf(e0[k], wr[k], g);
#pragma unroll
        for (int k = 0; k < 64; ++k) g = fmaf(e1[k], wr[64 + k], g);
        g = g * __builtin_amdgcn_rcpf(1.f + __expf(-g));
        l0 = fmaf(g, Wg2[u * 2 + 0], l0);
        l1 = fmaf(g, Wg2[u * 2 + 1], l1);
    }

    // softmax over 2 with temperature exp(gtemp): w1 = sigmoid((l1-l0)/T)
    float invT = __builtin_amdgcn_rcpf(__expf(gtemp[0]));
    float d = (l1 - l0) * invT;
    float w1 = __builtin_amdgcn_rcpf(1.f + __expf(-d));
    float w0 = 1.f - w1;

    // fused = w0*e0 + w1*e1 (overwrite e0), LayerNorm stats (two-pass var)
    float sum = 0.f;
#pragma unroll
    for (int k = 0; k < 64; ++k) {
        float f = fmaf(w0, e0[k], w1 * e1[k]);
        e0[k] = f;
        sum += f;
    }
    float mu = sum * (1.f / 64.f);
    float var = 0.f;
#pragma unroll
    for (int k = 0; k < 64; ++k) {
        float dfl = e0[k] - mu;
        var = fmaf(dfl, dfl, var);
    }
    var *= (1.f / 64.f);
    float rs = __builtin_amdgcn_rsqf(var + 1e-5f);

    // out = sum_k ((f-mu)*rs*ln_g[k] + ln_b[k]) * Wo[k] + bo
    //     = rs*(dot(f, gw) - mu*C1) + C0 + bo
    float dot = 0.f;
#pragma unroll
    for (int k = 0; k < 64; ++k) dot = fmaf(e0[k], g_gw[k], dot);
    out[p] = fmaf(rs, dot - mu * g_cc[1], g_cc[0] + bo[0]);
}

extern "C" void kernel_launch(void* const* d_in, const int* in_sizes, int n_in,
                              void* d_out, int out_size, void* d_ws, size_t ws_size,
                              hipStream_t stream)
{
    const float* coords = (const float*)d_in[0];
    const float* cost   = (const float*)d_in[1];
    const float* lscale = (const float*)d_in[2];
    const float* W1     = (const float*)d_in[3];
    const float* b1     = (const float*)d_in[4];
    const float* W2     = (const float*)d_in[5];
    const float* b2     = (const float*)d_in[6];
    const float* fg     = (const float*)d_in[7];
    const float* fb     = (const float*)d_in[8];
    const float* Wg1    = (const float*)d_in[9];
    const float* bg1    = (const float*)d_in[10];
    const float* Wg2    = (const float*)d_in[11];
    const float* bg2    = (const float*)d_in[12];
    const float* gt     = (const float*)d_in[13];
    const float* lng    = (const float*)d_in[14];
    const float* lnb    = (const float*)d_in[15];
    const float* Wo     = (const float*)d_in[16];
    const float* bo     = (const float*)d_in[17];
    float* out = (float*)d_out;

    prep_kernel<<<1, THREADS, 0, stream>>>(W1, b1, Wg1, lng, lnb, Wo);
    fused_kernel<<<NPAIR / THREADS, THREADS, 0, stream>>>(
        coords, cost, lscale, W2, b2, fg, fb, bg1, Wg2, bg2, gt, bo, out);
}

// Round 2
// 491.607 us; speedup vs baseline: 1.0009x; 1.0009x over previous
//
#include <hip/hip_runtime.h>
#include <math.h>

#define THREADS 256
#define NPAIR (8*256*256)

// Packed weights built by prep_kernel (avoids depending on ws_size).
// g_W1T[k][0..8] = W1[:,k], g_W1T[k][9] = b1[k], rest 0.  (64 rows x 16 floats)
__device__ float g_W1T[64 * 16];
// g_Wg1T[u][j] = Wg1[j][u]   (64 rows x 128 floats)
__device__ float g_Wg1T[64 * 128];
// g_gw[k] = ln_gamma[k] * Wo[k]
__device__ float g_gw[64];
// g_cc[0] = sum_k ln_beta[k]*Wo[k], g_cc[1] = sum_k ln_gamma[k]*Wo[k]
__device__ float g_cc[2];

__global__ void prep_kernel(const float* __restrict__ W1, const float* __restrict__ b1,
                            const float* __restrict__ Wg1,
                            const float* __restrict__ ln_g, const float* __restrict__ ln_b,
                            const float* __restrict__ Wo)
{
    int t = threadIdx.x;
    for (int i = t; i < 64 * 16; i += THREADS) {
        int k = i >> 4, j = i & 15;
        float v = 0.f;
        if (j < 9)       v = W1[j * 64 + k];
        else if (j == 9) v = b1[k];
        g_W1T[i] = v;
    }
    for (int i = t; i < 64 * 128; i += THREADS) {
        int u = i >> 7, j = i & 127;
        g_Wg1T[i] = Wg1[j * 64 + u];
    }
    if (t < 64) g_gw[t] = ln_g[t] * Wo[t];
    if (t == 0) {
        float c0 = 0.f, c1 = 0.f;
        for (int k = 0; k < 64; ++k) { c0 += ln_b[k] * Wo[k]; c1 += ln_g[k] * Wo[k]; }
        g_cc[0] = c0; g_cc[1] = c1;
    }
}

__device__ __forceinline__ void build_feat(float x, float s, float xf[9])
{
    xf[0] = x * s;
#pragma unroll
    for (int q = 0; q < 4; ++q) {
        float f = (float)(1 << q);
        xf[1 + 2 * q] = __sinf(x * f) * s;
        xf[2 + 2 * q] = __cosf(x * f) * s;
    }
}

// e[c] = film: silu(x@W1+b1) @ W2 + b2, then *fg + fb.  L1 fused into the k-loop.
__device__ __forceinline__ void encode_channel(const float xf[9],
                                               const float* __restrict__ W2,
                                               const float* __restrict__ b2,
                                               const float* __restrict__ fg,
                                               const float* __restrict__ fb,
                                               float e[64])
{
#pragma unroll
    for (int c = 0; c < 64; ++c) e[c] = b2[c];
    for (int k = 0; k < 64; ++k) {            // dynamic loop: small I-cache footprint
        const float* w1r = &g_W1T[k * 16];    // uniform address -> s_load
        float h = w1r[9];
#pragma unroll
        for (int j = 0; j < 9; ++j) h = fmaf(xf[j], w1r[j], h);
        // silu(h) = h * sigmoid(h)
        h = h * __builtin_amdgcn_rcpf(1.f + __expf(-h));
        const float* w2r = W2 + k * 64;       // uniform address -> s_load
#pragma unroll
        for (int c = 0; c < 64; ++c) e[c] = fmaf(h, w2r[c], e[c]);
    }
#pragma unroll
    for (int c = 0; c < 64; ++c) e[c] = fmaf(e[c], fg[c], fb[c]);
}

// (256, 2): cap VGPRs at 256 so e0[64]+e1[64] live entirely in registers.
// R1 evidence: default bound gave VGPR=76 + scratch spills -> Occupancy 31.7%,
// VALUBusy 56%. 2 waves/SIMD with 64 independent FMA chains is latency-tolerant.
__global__ __launch_bounds__(THREADS, 2) void fused_kernel(
    const float* __restrict__ coords, const float* __restrict__ cost,
    const float* __restrict__ lscale,
    const float* __restrict__ W2, const float* __restrict__ b2,
    const float* __restrict__ fgam, const float* __restrict__ fbet,
    const float* __restrict__ bg1, const float* __restrict__ Wg2,
    const float* __restrict__ bg2, const float* __restrict__ gtemp,
    const float* __restrict__ bo,
    float* __restrict__ out)
{
    int p = blockIdx.x * THREADS + threadIdx.x;
    int b = p >> 16;
    int ij = p & 0xFFFF;
    int i = ij >> 8, j = ij & 255;

    float c = cost[p];
    const float* cb = coords + (b << 9);      // 256*2 floats per batch
    float xi = cb[2 * i], yi = cb[2 * i + 1];
    float xj = cb[2 * j], yj = cb[2 * j + 1];
    float ang = atan2f(yi - yj, xi - xj);     // diff[...,1]=dy, diff[...,0]=dx

    float s0 = __expf(lscale[0]);
    float s1 = __expf(lscale[1]);

    float xf[9];
    float e0[64], e1[64];

    build_feat(c, s0, xf);
    encode_channel(xf, W2, b2, fgam, fbet, e0);
    build_feat(ang, s1, xf);
    encode_channel(xf, W2, b2, fgam + 64, fbet + 64, e1);

    // Gate: logits = silu([e0|e1] @ Wg1 + bg1) @ Wg2 + bg2  (g_u streamed, never stored)
    float l0 = bg2[0], l1 = bg2[1];
    for (int u = 0; u < 64; ++u) {
        const float* wr = &g_Wg1T[u * 128];   // uniform -> s_load
        float g = bg1[u];
#pragma unroll
        for (int k = 0; k < 64; ++k) g = fmaf(e0[k], wr[k], g);
#pragma unroll
        for (int k = 0; k < 64; ++k) g = fmaf(e1[k], wr[64 + k], g);
        g = g * __builtin_amdgcn_rcpf(1.f + __expf(-g));
        l0 = fmaf(g, Wg2[u * 2 + 0], l0);
        l1 = fmaf(g, Wg2[u * 2 + 1], l1);
    }

    // softmax over 2 with temperature exp(gtemp): w1 = sigmoid((l1-l0)/T)
    float invT = __builtin_amdgcn_rcpf(__expf(gtemp[0]));
    float d = (l1 - l0) * invT;
    float w1 = __builtin_amdgcn_rcpf(1.f + __expf(-d));
    float w0 = 1.f - w1;

    // fused = w0*e0 + w1*e1 (overwrite e0), LayerNorm stats (two-pass var)
    float sum = 0.f;
#pragma unroll
    for (int k = 0; k < 64; ++k) {
        float f = fmaf(w0, e0[k], w1 * e1[k]);
        e0[k] = f;
        sum += f;
    }
    float mu = sum * (1.f / 64.f);
    float var = 0.f;
#pragma unroll
    for (int k = 0; k < 64; ++k) {
        float dfl = e0[k] - mu;
        var = fmaf(dfl, dfl, var);
    }
    var *= (1.f / 64.f);
    float rs = __builtin_amdgcn_rsqf(var + 1e-5f);

    // out = sum_k ((f-mu)*rs*ln_g[k] + ln_b[k]) * Wo[k] + bo
    //     = rs*(dot(f, gw) - mu*C1) + C0 + bo
    float dot = 0.f;
#pragma unroll
    for (int k = 0; k < 64; ++k) dot = fmaf(e0[k], g_gw[k], dot);
    out[p] = fmaf(rs, dot - mu * g_cc[1], g_cc[0] + bo[0]);
}

extern "C" void kernel_launch(void* const* d_in, const int* in_sizes, int n_in,
                              void* d_out, int out_size, void* d_ws, size_t ws_size,
                              hipStream_t stream)
{
    const float* coords = (const float*)d_in[0];
    const float* cost   = (const float*)d_in[1];
    const float* lscale = (const float*)d_in[2];
    const float* W1     = (const float*)d_in[3];
    const float* b1     = (const float*)d_in[4];
    const float* W2     = (const float*)d_in[5];
    const float* b2     = (const float*)d_in[6];
    const float* fg     = (const float*)d_in[7];
    const float* fb     = (const float*)d_in[8];
    const float* Wg1    = (const float*)d_in[9];
    const float* bg1    = (const float*)d_in[10];
    const float* Wg2    = (const float*)d_in[11];
    const float* bg2    = (const float*)d_in[12];
    const float* gt     = (const float*)d_in[13];
    const float* lng    = (const float*)d_in[14];
    const float* lnb    = (const float*)d_in[15];
    const float* Wo     = (const float*)d_in[16];
    const float* bo     = (const float*)d_in[17];
    float* out = (float*)d_out;

    prep_kernel<<<1, THREADS, 0, stream>>>(W1, b1, Wg1, lng, lnb, Wo);
    fused_kernel<<<NPAIR / THREADS, THREADS, 0, stream>>>(
        coords, cost, lscale, W2, b2, fg, fb, bg1, Wg2, bg2, gt, bo, out);
}